// Round 11
// baseline (367.116 us; speedup 1.0000x reference)
//
#include <hip/hip_runtime.h>
#include <hip/hip_bf16.h>
#include <stdint.h>
#include <string.h>

#define D_MODEL 768
#define H_HEADS 12
#define HD_ 64
#define N_QKV 2304

typedef __bf16 bf16x8 __attribute__((ext_vector_type(8)));
typedef float f32x4 __attribute__((ext_vector_type(4)));
typedef __attribute__((address_space(3))) char lds_char;

__device__ __forceinline__ unsigned short f2bfbits(float f) {
  union { float f; unsigned u; } x; x.f = f;
  unsigned r = x.u + 0x7fffu + ((x.u >> 16) & 1u);
  return (unsigned short)(r >> 16);
}

// pack two non-negative floats to bf16 pair
__device__ __forceinline__ unsigned pk2(float a, float b) {
  union { float f; unsigned u; } x, y; x.f = a; y.f = b;
  return ((x.u + 0x8000u) >> 16) | ((y.u + 0x8000u) & 0xffff0000u);
}

// async global->LDS, 16B/lane; LDS dest = wave-uniform base + lane*16
__device__ __forceinline__ void gload_lds16(const void* g, void* l) {
  __builtin_amdgcn_global_load_lds(
      (const __attribute__((address_space(1))) unsigned int*)g,
      (__attribute__((address_space(3))) unsigned int*)l, 16, 0, 0);
}

// inline-asm ds_read_b128: invisible to the LDS-DMA alias tracker -> no
// compiler-inserted vmcnt(0) drains (R3/R7-verified). Ordering owned by the
// explicit vmcnt/lgkmcnt + sched_barrier pins (rule #18).
#define DSR(dst, ptr, IMM) \
  asm volatile("ds_read_b128 %0, %1 offset:%2" : "=v"(dst) : "v"(ptr), "n"(IMM))

#define FENCE_() __builtin_amdgcn_sched_barrier(0)
// clobberless sync (no "memory" -> no forced vmcnt drain; R1->R2 proven)
__device__ __forceinline__ void store_sync() {
  FENCE_();
  asm volatile("s_waitcnt lgkmcnt(0)");
  FENCE_();
  __builtin_amdgcn_s_barrier();
  FENCE_();
}

// ---------------- weight transpose + fp32->bf16 ----------------
__global__ void transpose_w(const float* __restrict__ in, unsigned short* __restrict__ out,
                            int R, int C) {
  __shared__ float tile[32][33];
  int c0 = blockIdx.x * 32, r0 = blockIdx.y * 32;
  int tx = threadIdx.x, ty = threadIdx.y;
#pragma unroll
  for (int i = 0; i < 32; i += 8)
    tile[ty + i][tx] = in[(size_t)(r0 + ty + i) * C + c0 + tx];
  __syncthreads();
#pragma unroll
  for (int i = 0; i < 32; i += 8)
    out[(size_t)(c0 + ty + i) * R + r0 + tx] = f2bfbits(tile[tx][ty + i]);
}

// ---------------- V transpose with per-64-token key permute ----------------
__global__ void transpose_v(const unsigned short* __restrict__ qkv,
                            unsigned short* __restrict__ vT, int M) {
  __shared__ unsigned short tile[32][33];
  int t0 = blockIdx.x * 32, c0 = blockIdx.y * 32;
  int tx = threadIdx.x, ty = threadIdx.y;
#pragma unroll
  for (int i = 0; i < 32; i += 8)
    tile[ty + i][tx] = qkv[(size_t)(t0 + ty + i) * N_QKV + 1536 + c0 + tx];
  __syncthreads();
  int t = t0 + tx;
  int c = t & 63;
  int kp = ((c >> 5) << 5) | (((c >> 2) & 3) << 3) | (((c >> 4) & 1) << 2) | (c & 3);
  size_t col = (size_t)(t & ~63) + kp;
#pragma unroll
  for (int i = 0; i < 32; i += 8)
    vT[(size_t)(c0 + ty + i) * M + col] = tile[tx][ty + i];
}

// ---------------- layernorm -> bf16 ----------------
__global__ void ln_bf16(const float* __restrict__ x, const float* __restrict__ g,
                        const float* __restrict__ be, unsigned short* __restrict__ out) {
  int row = blockIdx.x;
  const float* xr = x + (size_t)row * D_MODEL;
  int t = threadIdx.x;
  float v0 = xr[t], v1 = xr[t + 256], v2 = xr[t + 512];
  float s = v0 + v1 + v2;
  float s2 = v0 * v0 + v1 * v1 + v2 * v2;
#pragma unroll
  for (int off = 32; off > 0; off >>= 1) {
    s += __shfl_down(s, off, 64);
    s2 += __shfl_down(s2, off, 64);
  }
  __shared__ float red[8];
  int w = t >> 6, lane = t & 63;
  if (lane == 0) { red[w] = s; red[w + 4] = s2; }
  __syncthreads();
  if (t == 0) {
    float a = red[0] + red[1] + red[2] + red[3];
    float b = red[4] + red[5] + red[6] + red[7];
    red[0] = a * (1.0f / 768.0f);
    red[4] = b * (1.0f / 768.0f);
  }
  __syncthreads();
  float mu = red[0];
  float var = red[4] - mu * mu;
  float rs = rsqrtf(var + 1e-6f);
  unsigned short* orow = out + (size_t)row * D_MODEL;
  orow[t]       = f2bfbits((v0 - mu) * rs * g[t]       + be[t]);
  orow[t + 256] = f2bfbits((v1 - mu) * rs * g[t + 256] + be[t + 256]);
  orow[t + 512] = f2bfbits((v2 - mu) * rs * g[t + 512] + be[t + 512]);
}

// ---------------- bf16 MFMA GEMM 128x128, 2-wave fat tile (QKV, FC1) --------
// R11 = R10 with the LDS buffer stride fixed: each buffer is 128x32 bf16 =
// 8192 B (R10 used 16384 -> buffer-1 writes landed in lB -> NaN).
// Mechanism: LDS-BW-bound (133 B/cyc vs 112 ceiling). 2 waves x (64x128
// per-wave tile) raises FLOP/LDS-byte 21.8 -> 26.2; 4 indep 2-wave
// blocks/CU. Same R7 DMA substep loop (vmcnt(8): 8 loads/stage/wave).
template <int EPI>
__global__ void __launch_bounds__(128, 2)
gemm_rs(const unsigned short* __restrict__ A,
        const unsigned short* __restrict__ Bt,
        const float* __restrict__ bias,
        const float* __restrict__ res,
        void* __restrict__ outv,
        int M, int N, int K) {
  __shared__ unsigned short lA[2][128 * 32];
  __shared__ unsigned short lB[2][128 * 32];
  int tid = threadIdx.x;
  int w = tid >> 6, lane = tid & 63;
  int id = blockIdx.x;
  int nn = N >> 7, bandM = (M >> 7) >> 3;
  int xcd = id & 7, s = id >> 3;
  int mt = xcd * bandM + s / nn;
  int nt = s - (s / nn) * nn;
  int m0 = mt * 128, n0 = nt * 128;
  f32x4 acc[4][8];
#pragma unroll
  for (int i = 0; i < 4; i++)
#pragma unroll
    for (int j = 0; j < 8; j++) acc[i][j] = (f32x4){0.f, 0.f, 0.f, 0.f};

  int fm = lane & 15, fg = lane >> 4;

  // staging: wave w covers rows w*64 + j*16 + (lane>>2), j=0..3, for A and B.
  // source chunk sc0 = (lane&3) ^ ((lane>>3)&3); dest = base + lane*16 (linear
  // = row-major slot (row*64 + slot*16) for row=w*64+j*16+(lane>>2), slot=lane&3).
  int sc0 = (lane & 3) ^ ((lane >> 3) & 3);
  const unsigned short* gAs = A + (size_t)(m0 + w * 64 + (lane >> 2)) * K + sc0 * 8;
  const unsigned short* gBs = Bt + (size_t)(n0 + w * 64 + (lane >> 2)) * K + sc0 * 8;
  char* lA0 = (char*)&lA[0][0];
  char* lB0 = (char*)&lB[0][0];
  int wo = w * 4096;
  int nk = K >> 5;

  auto stage = [&](int kt, int buf) {
    int kk = kt < nk ? kt : nk - 1;      // clamp: uniform vmcnt accounting
    int off = kk * 32;
#pragma unroll
    for (int j = 0; j < 4; ++j)
      gload_lds16(gAs + off + (size_t)(j * 16) * K, lA0 + buf * 8192 + wo + j * 1024);
#pragma unroll
    for (int j = 0; j < 4; ++j)
      gload_lds16(gBs + off + (size_t)(j * 16) * K, lB0 + buf * 8192 + wo + j * 1024);
  };

  // fragment bases: af rows w*64+i*16+fm (own half), bfr rows j*16+fm (all 128)
  const unsigned aoff0 = (unsigned)(w * 4096 + fm * 64 + ((((fm >> 1) & 3) ^ fg) * 16));
  const unsigned boff0 = (unsigned)(fm * 64 + ((((fm >> 1) & 3) ^ fg) * 16));

  stage(0, 0);
  stage(1, 1);   // 16 outstanding per wave

  for (int k = 0; k < nk; ++k) {
    int cur = k & 1;
    asm volatile("s_waitcnt vmcnt(8)");   // stage(k) landed; stage(k+1) in flight
    FENCE_();
    __builtin_amdgcn_s_barrier();         // both waves' DMA for buf[cur] done
    FENCE_();
    bf16x8 af[4], bfr[8];
    const lds_char* pa = (const lds_char*)(lA0 + cur * 8192 + aoff0);
    const lds_char* pb = (const lds_char*)(lB0 + cur * 8192 + boff0);
    DSR(af[0], pa, 0); DSR(af[1], pa, 1024); DSR(af[2], pa, 2048); DSR(af[3], pa, 3072);
    DSR(bfr[0], pb, 0);    DSR(bfr[1], pb, 1024); DSR(bfr[2], pb, 2048); DSR(bfr[3], pb, 3072);
    DSR(bfr[4], pb, 4096); DSR(bfr[5], pb, 5120); DSR(bfr[6], pb, 6144); DSR(bfr[7], pb, 7168);
    asm volatile("s_waitcnt lgkmcnt(0)");
    FENCE_();
    __builtin_amdgcn_s_barrier();         // all reads done -> buf[cur] reusable
    FENCE_();
    stage(k + 2, cur);
    FENCE_();
#pragma unroll
    for (int i = 0; i < 4; ++i)
#pragma unroll
      for (int j = 0; j < 8; ++j)
        acc[i][j] = __builtin_amdgcn_mfma_f32_16x16x32_bf16(af[i], bfr[j], acc[i][j], 0, 0, 0);
  }
  asm volatile("s_waitcnt vmcnt(0)");     // drain DMA before exit
  FENCE_();

  int er = fg * 4, ec = fm;
#pragma unroll
  for (int i = 0; i < 4; i++) {
#pragma unroll
    for (int j = 0; j < 8; j++) {
      int n = n0 + j * 16 + ec;
      float bv = bias[n];
#pragma unroll
      for (int r = 0; r < 4; r++) {
        int m = m0 + w * 64 + i * 16 + er + r;
        float v = acc[i][j][r] + bv;
        if (EPI == 1) {
          v += res[(size_t)m * N + n];
          ((float*)outv)[(size_t)m * N + n] = v;
        } else {
          if (EPI == 2) v = 0.5f * v * (1.0f + erff(v * 0.70710678118f));
          ((unsigned short*)outv)[(size_t)m * N + n] = f2bfbits(v);
        }
      }
    }
  }
}

// ---------------- bf16 MFMA GEMM 128x64, register-staged (Wo, FC2) ----------
// R8-proven best for the N=768 GEMMs (65us vs DMA's 71 at 2- and 3-deep).
template <int EPI>
__global__ void __launch_bounds__(256, 4)
gemm_n64(const unsigned short* __restrict__ A,
         const unsigned short* __restrict__ Bt,
         const float* __restrict__ bias,
         const float* __restrict__ res,
         void* __restrict__ outv,
         int M, int N, int K) {
  __shared__ unsigned short lA[2][128 * 32];
  __shared__ unsigned short lB[2][64 * 32];
  int tid = threadIdx.x;
  int w = tid >> 6, lane = tid & 63;
  int id = blockIdx.x;
  int nn = N >> 6, bandM = (M >> 7) >> 3;
  int xcd = id & 7, s = id >> 3;
  int mt = xcd * bandM + s / nn;
  int nt = s - (s / nn) * nn;
  int m0 = mt * 128, n0 = nt * 64;
  int wm = w * 32;
  f32x4 acc[2][4];
#pragma unroll
  for (int i = 0; i < 2; i++)
#pragma unroll
    for (int j = 0; j < 4; j++) acc[i][j] = (f32x4){0.f, 0.f, 0.f, 0.f};

  int sr = tid >> 2, sc = tid & 3;
  const unsigned short* gA = A + (size_t)(m0 + sr) * K + sc * 8;
  const unsigned short* gB = Bt + (size_t)(n0 + sr) * K + sc * 8;  // sr<64: whole B tile
  int wOff = sr * 64 + ((((sr >> 1) & 3) ^ sc) * 16);
  int fm = lane & 15, fg = lane >> 4;

  uint4 pA0, pA1, pB0;
  uint4 qA0, qA1, qB0;

  int nk = K >> 5;
  pA0 = *(const uint4*)(gA);
  pA1 = *(const uint4*)(gA + (size_t)64 * K);
  pB0 = *(const uint4*)(gB);
  qA0 = *(const uint4*)(gA + 32);
  qA1 = *(const uint4*)(gA + (size_t)64 * K + 32);
  qB0 = *(const uint4*)(gB + 32);

  for (int k = 0; k < nk; k += 2) {
    {
      char* la = (char*)&lA[0][0];
      char* lb = (char*)&lB[0][0];
      *(uint4*)(la + wOff) = pA0;
      *(uint4*)(la + wOff + 4096) = pA1;
      *(uint4*)(lb + wOff) = pB0;
      if (k + 2 < nk) {
        int k0 = (k + 2) * 32;
        pA0 = *(const uint4*)(gA + k0);
        pA1 = *(const uint4*)(gA + (size_t)64 * K + k0);
        pB0 = *(const uint4*)(gB + k0);
      }
      store_sync();
      bf16x8 af[2], bfr[4];
#pragma unroll
      for (int i = 0; i < 2; i++) {
        int rr = wm + i * 16 + fm;
        af[i] = *(const bf16x8*)(la + rr * 64 + ((((rr >> 1) & 3) ^ fg) * 16));
      }
#pragma unroll
      for (int j = 0; j < 4; j++) {
        int rr = j * 16 + fm;
        bfr[j] = *(const bf16x8*)(lb + rr * 64 + ((((rr >> 1) & 3) ^ fg) * 16));
      }
#pragma unroll
      for (int i = 0; i < 2; i++)
#pragma unroll
        for (int j = 0; j < 4; j++)
          acc[i][j] = __builtin_amdgcn_mfma_f32_16x16x32_bf16(af[i], bfr[j], acc[i][j], 0, 0, 0);
      store_sync();
    }
    {
      char* la = (char*)&lA[1][0];
      char* lb = (char*)&lB[1][0];
      *(uint4*)(la + wOff) = qA0;
      *(uint4*)(la + wOff + 4096) = qA1;
      *(uint4*)(lb + wOff) = qB0;
      if (k + 3 < nk) {
        int k0 = (k + 3) * 32;
        qA0 = *(const uint4*)(gA + k0);
        qA1 = *(const uint4*)(gA + (size_t)64 * K + k0);
        qB0 = *(const uint4*)(gB + k0);
      }
      store_sync();
      bf16x8 af[2], bfr[4];
#pragma unroll
      for (int i = 0; i < 2; i++) {
        int rr = wm + i * 16 + fm;
        af[i] = *(const bf16x8*)(la + rr * 64 + ((((rr >> 1) & 3) ^ fg) * 16));
      }
#pragma unroll
      for (int j = 0; j < 4; j++) {
        int rr = j * 16 + fm;
        bfr[j] = *(const bf16x8*)(lb + rr * 64 + ((((rr >> 1) & 3) ^ fg) * 16));
      }
#pragma unroll
      for (int i = 0; i < 2; i++)
#pragma unroll
        for (int j = 0; j < 4; j++)
          acc[i][j] = __builtin_amdgcn_mfma_f32_16x16x32_bf16(af[i], bfr[j], acc[i][j], 0, 0, 0);
      store_sync();
    }
  }

  int er = (lane >> 4) * 4, ec = lane & 15;
#pragma unroll
  for (int i = 0; i < 2; i++) {
#pragma unroll
    for (int j = 0; j < 4; j++) {
      int n = n0 + j * 16 + ec;
      float bv = bias[n];
#pragma unroll
      for (int r = 0; r < 4; r++) {
        int m = m0 + wm + i * 16 + er + r;
        float v = acc[i][j][r] + bv;
        if (EPI == 1) {
          v += res[(size_t)m * N + n];
          ((float*)outv)[(size_t)m * N + n] = v;
        } else {
          if (EPI == 2) v = 0.5f * v * (1.0f + erff(v * 0.70710678118f));
          ((unsigned short*)outv)[(size_t)m * N + n] = f2bfbits(v);
        }
      }
    }
  }
}

// ---------------- ragged flash attention v4 (unchanged) ---------------------
__global__ void attn_flash4(const unsigned short* __restrict__ qkv,
                            const unsigned short* __restrict__ vT,
                            const int* __restrict__ cu,
                            unsigned short* __restrict__ out, int M) {
  int id = blockIdx.x;
  int qc = id / 96;
  int bh = id - qc * 96;
  int b = bh / 12, h = bh - b * 12;
  int tok0 = cu[b];
  int len = cu[b + 1] - tok0;
  if (qc * 128 >= len) return;

  __shared__ unsigned short lK[2][64 * 64];
  __shared__ unsigned short lVT[2][64 * 64];

  int tid = threadIdx.x, w = tid >> 6, lane = tid & 63;
  int fm = lane & 15, fg = lane >> 4;
  int xm = fm & 7;
  int qbase = qc * 128 + w * 32;

  bf16x8 qf[2][2];
#pragma unroll
  for (int qs = 0; qs < 2; qs++)
#pragma unroll
    for (int kh = 0; kh < 2; kh++)
      qf[qs][kh] = *(const bf16x8*)(qkv + (size_t)(tok0 + qbase + qs * 16 + fm) * N_QKV +
                                    h * 64 + kh * 32 + fg * 8);

  f32x4 Oacc[2][4];
#pragma unroll
  for (int qs = 0; qs < 2; qs++)
#pragma unroll
    for (int dt = 0; dt < 4; dt++) Oacc[qs][dt] = (f32x4){0.f, 0.f, 0.f, 0.f};
  float lrow[2] = {0.f, 0.f};
  const float C2 = 0.18033688011112042f;  // log2(e)/sqrt(64)

  int sr = tid >> 3, sp = tid & 7, sl = sp ^ (sr & 7);
  const unsigned short* kg0 = qkv + D_MODEL + h * 64 + sl * 8;
  const unsigned short* vg0 = vT + (size_t)(h * 64 + sr) * M + tok0 + sl * 8;

  uint4 rk0, rk1, rv0, rv1;
  auto gload = [&](int kt) {
    rk0 = *(const uint4*)(kg0 + (size_t)(tok0 + kt + sr) * N_QKV);
    rk1 = *(const uint4*)(kg0 + (size_t)(tok0 + kt + sr + 32) * N_QKV);
    rv0 = *(const uint4*)(vg0 + kt);
    rv1 = *(const uint4*)(vg0 + (size_t)32 * M + kt);
  };

  int nkt = len >> 6;
  gload(0);
  for (int kt = 0; kt < nkt; kt++) {
    int cur = kt & 1;
    *(uint4*)((char*)&lK[cur][0] + tid * 16) = rk0;
    *(uint4*)((char*)&lK[cur][0] + tid * 16 + 4096) = rk1;
    *(uint4*)((char*)&lVT[cur][0] + tid * 16) = rv0;
    *(uint4*)((char*)&lVT[cur][0] + tid * 16 + 4096) = rv1;
    if (kt + 1 < nkt) gload((kt + 1) * 64);
    store_sync();

    f32x4 s[2][4];
#pragma unroll
    for (int qs = 0; qs < 2; qs++)
#pragma unroll
      for (int t = 0; t < 4; t++) s[qs][t] = (f32x4){0.f, 0.f, 0.f, 0.f};
#pragma unroll
    for (int t = 0; t < 4; t++) {
      bf16x8 kf0 = *(const bf16x8*)&lK[cur][(t * 16 + fm) * 64 + ((fg ^ xm) * 8)];
      bf16x8 kf1 = *(const bf16x8*)&lK[cur][(t * 16 + fm) * 64 + (((4 + fg) ^ xm) * 8)];
#pragma unroll
      for (int qs = 0; qs < 2; qs++) {
        s[qs][t] = __builtin_amdgcn_mfma_f32_16x16x32_bf16(kf0, qf[qs][0], s[qs][t], 0, 0, 0);
        s[qs][t] = __builtin_amdgcn_mfma_f32_16x16x32_bf16(kf1, qf[qs][1], s[qs][t], 0, 0, 0);
      }
    }

    union { bf16x8 v; unsigned u[4]; } af[2][2];
#pragma unroll
    for (int qs = 0; qs < 2; qs++) {
      float ssum = 0.f;
#pragma unroll
      for (int t = 0; t < 4; t++) {
#pragma unroll
        for (int r = 0; r < 4; r++) {
          float p = exp2f(s[qs][t][r] * C2);
          s[qs][t][r] = p;
          ssum += p;
        }
      }
      lrow[qs] += ssum;
      af[qs][0].u[0] = pk2(s[qs][0][0], s[qs][0][1]);
      af[qs][0].u[1] = pk2(s[qs][0][2], s[qs][0][3]);
      af[qs][0].u[2] = pk2(s[qs][1][0], s[qs][1][1]);
      af[qs][0].u[3] = pk2(s[qs][1][2], s[qs][1][3]);
      af[qs][1].u[0] = pk2(s[qs][2][0], s[qs][2][1]);
      af[qs][1].u[1] = pk2(s[qs][2][2], s[qs][2][3]);
      af[qs][1].u[2] = pk2(s[qs][3][0], s[qs][3][1]);
      af[qs][1].u[3] = pk2(s[qs][3][2], s[qs][3][3]);
    }

#pragma unroll
    for (int dt = 0; dt < 4; dt++) {
      bf16x8 vf0 = *(const bf16x8*)&lVT[cur][(dt * 16 + fm) * 64 + ((fg ^ xm) * 8)];
      bf16x8 vf1 = *(const bf16x8*)&lVT[cur][(dt * 16 + fm) * 64 + (((4 + fg) ^ xm) * 8)];
#pragma unroll
      for (int qs = 0; qs < 2; qs++) {
        Oacc[qs][dt] = __builtin_amdgcn_mfma_f32_16x16x32_bf16(af[qs][0].v, vf0, Oacc[qs][dt], 0, 0, 0);
        Oacc[qs][dt] = __builtin_amdgcn_mfma_f32_16x16x32_bf16(af[qs][1].v, vf1, Oacc[qs][dt], 0, 0, 0);
      }
    }
  }

#pragma unroll
  for (int qs = 0; qs < 2; qs++) {
    lrow[qs] += __shfl_xor(lrow[qs], 16, 64);
    lrow[qs] += __shfl_xor(lrow[qs], 32, 64);
    float inv = 1.0f / lrow[qs];
    float ir[4];
#pragma unroll
    for (int r = 0; r < 4; r++) ir[r] = __shfl(inv, fg * 4 + r, 64);
#pragma unroll
    for (int dt = 0; dt < 4; dt++)
#pragma unroll
      for (int r = 0; r < 4; r++)
        out[(size_t)(tok0 + qbase + qs * 16 + fg * 4 + r) * D_MODEL + h * 64 + dt * 16 + fm] =
            f2bfbits(Oacc[qs][dt][r] * ir[r]);
  }
}

extern "C" void kernel_launch(void* const* d_in, const int* in_sizes, int n_in,
                              void* d_out, int out_size, void* d_ws, size_t ws_size,
                              hipStream_t stream) {
  const float* x    = (const float*)d_in[0];
  const int* cu     = (const int*)d_in[1];
  const float* g1   = (const float*)d_in[2];
  const float* be1  = (const float*)d_in[3];
  const float* Wqkv = (const float*)d_in[4];
  const float* bqkv = (const float*)d_in[5];
  const float* Wo   = (const float*)d_in[6];
  const float* bo   = (const float*)d_in[7];
  const float* g2   = (const float*)d_in[8];
  const float* be2  = (const float*)d_in[9];
  const float* W1   = (const float*)d_in[10];
  const float* bfc1 = (const float*)d_in[11];
  const float* W2   = (const float*)d_in[12];
  const float* bfc2 = (const float*)d_in[13];
  float* out = (float*)d_out;
  int M = in_sizes[0] / D_MODEL;  // 6144

  unsigned short* WqkvT = (unsigned short*)d_ws;                       // 2304x768
  unsigned short* WoT   = WqkvT + 2304 * 768;                          // 768x768
  unsigned short* W1T   = WoT + 768 * 768;                             // 3072x768
  unsigned short* W2T   = W1T + 3072 * 768;                            // 768x3072
  unsigned short* bufA  = W2T + 768 * 3072;                            // M x 768 bf16
  float* x1             = (float*)(bufA + (size_t)M * D_MODEL);        // M x 768 f32
  unsigned short* qkvb  = (unsigned short*)(x1 + (size_t)M * D_MODEL); // M x 2304/3072 bf16
  unsigned short* vT = (unsigned short*)x1;  // overlaps x1 (dead before Wo-gemm)

  dim3 b32(32, 8);
  transpose_w<<<dim3(2304 / 32, 768 / 32), b32, 0, stream>>>(Wqkv, WqkvT, 768, 2304);
  transpose_w<<<dim3(768 / 32, 768 / 32), b32, 0, stream>>>(Wo, WoT, 768, 768);
  transpose_w<<<dim3(3072 / 32, 768 / 32), b32, 0, stream>>>(W1, W1T, 768, 3072);
  transpose_w<<<dim3(768 / 32, 3072 / 32), b32, 0, stream>>>(W2, W2T, 3072, 768);

  ln_bf16<<<M, 256, 0, stream>>>(x, g1, be1, bufA);
  gemm_rs<0><<<(2304 / 128) * (M / 128), 128, 0, stream>>>(bufA, WqkvT, bqkv, nullptr, qkvb, M, 2304, 768);
  transpose_v<<<dim3(M / 32, 768 / 32), b32, 0, stream>>>(qkvb, vT, M);
  attn_flash4<<<8 * 96, 256, 0, stream>>>(qkvb, vT, cu, bufA, M);
  gemm_n64<1><<<(768 / 64) * (M / 128), 256, 0, stream>>>(bufA, WoT, bo, x, x1, M, 768, 768);
  ln_bf16<<<M, 256, 0, stream>>>(x1, g2, be2, bufA);
  gemm_rs<2><<<(3072 / 128) * (M / 128), 128, 0, stream>>>(bufA, W1T, bfc1, nullptr, qkvb, M, 3072, 768);
  gemm_n64<1><<<(768 / 64) * (M / 128), 256, 0, stream>>>(qkvb, W2T, bfc2, x1, out, M, 768, 3072);
}

// Round 12
// 337.700 us; speedup vs baseline: 1.0871x; 1.0871x over previous
//
#include <hip/hip_runtime.h>
#include <hip/hip_bf16.h>
#include <stdint.h>
#include <string.h>

#define D_MODEL 768
#define H_HEADS 12
#define HD_ 64
#define N_QKV 2304

typedef __bf16 bf16x8 __attribute__((ext_vector_type(8)));
typedef float f32x4 __attribute__((ext_vector_type(4)));
typedef __attribute__((address_space(3))) char lds_char;

__device__ __forceinline__ unsigned short f2bfbits(float f) {
  union { float f; unsigned u; } x; x.f = f;
  unsigned r = x.u + 0x7fffu + ((x.u >> 16) & 1u);
  return (unsigned short)(r >> 16);
}

// pack two non-negative floats to bf16 pair
__device__ __forceinline__ unsigned pk2(float a, float b) {
  union { float f; unsigned u; } x, y; x.f = a; y.f = b;
  return ((x.u + 0x8000u) >> 16) | ((y.u + 0x8000u) & 0xffff0000u);
}

// async global->LDS, 16B/lane; LDS dest = wave-uniform base + lane*16
__device__ __forceinline__ void gload_lds16(const void* g, void* l) {
  __builtin_amdgcn_global_load_lds(
      (const __attribute__((address_space(1))) unsigned int*)g,
      (__attribute__((address_space(3))) unsigned int*)l, 16, 0, 0);
}

// inline-asm ds_read_b128: invisible to the LDS-DMA alias tracker -> no
// compiler-inserted vmcnt(0) drains (R3/R7-verified). Ordering owned by the
// explicit vmcnt/lgkmcnt + sched_barrier pins (rule #18).
#define DSR(dst, ptr, IMM) \
  asm volatile("ds_read_b128 %0, %1 offset:%2" : "=v"(dst) : "v"(ptr), "n"(IMM))

#define FENCE_() __builtin_amdgcn_sched_barrier(0)
// clobberless sync (no "memory" -> no forced vmcnt drain; R1->R2 proven)
__device__ __forceinline__ void store_sync() {
  FENCE_();
  asm volatile("s_waitcnt lgkmcnt(0)");
  FENCE_();
  __builtin_amdgcn_s_barrier();
  FENCE_();
}

// ---------------- fused weight transposes (4 launches -> 1) -----------------
// Linear block decode over the four (R,C) geometries; body identical to the
// old transpose_w 32x32 LDS tile. nb: 1728 + 576 + 2304 + 2304 = 6912.
__global__ void transpose_w4(const float* __restrict__ Wqkv, const float* __restrict__ Wo,
                             const float* __restrict__ W1,   const float* __restrict__ W2,
                             unsigned short* __restrict__ WqkvT, unsigned short* __restrict__ WoT,
                             unsigned short* __restrict__ W1T,   unsigned short* __restrict__ W2T) {
  __shared__ float tile[32][33];
  int id = blockIdx.x;
  const float* in; unsigned short* outp; int R, C, bx, by;
  if (id < 1728)      { in = Wqkv; outp = WqkvT; R = 768;  C = 2304; bx = id % 72;          by = id / 72; }
  else if (id < 2304) { int t = id - 1728; in = Wo; outp = WoT; R = 768;  C = 768;  bx = t % 24; by = t / 24; }
  else if (id < 4608) { int t = id - 2304; in = W1; outp = W1T; R = 768;  C = 3072; bx = t % 96; by = t / 96; }
  else                { int t = id - 4608; in = W2; outp = W2T; R = 3072; C = 768;  bx = t % 24; by = t / 24; }
  int c0 = bx * 32, r0 = by * 32;
  int tx = threadIdx.x, ty = threadIdx.y;
#pragma unroll
  for (int i = 0; i < 32; i += 8)
    tile[ty + i][tx] = in[(size_t)(r0 + ty + i) * C + c0 + tx];
  __syncthreads();
#pragma unroll
  for (int i = 0; i < 32; i += 8)
    outp[(size_t)(c0 + ty + i) * R + r0 + tx] = f2bfbits(tile[tx][ty + i]);
}

// ---------------- V transpose with per-64-token key permute ----------------
__global__ void transpose_v(const unsigned short* __restrict__ qkv,
                            unsigned short* __restrict__ vT, int M) {
  __shared__ unsigned short tile[32][33];
  int t0 = blockIdx.x * 32, c0 = blockIdx.y * 32;
  int tx = threadIdx.x, ty = threadIdx.y;
#pragma unroll
  for (int i = 0; i < 32; i += 8)
    tile[ty + i][tx] = qkv[(size_t)(t0 + ty + i) * N_QKV + 1536 + c0 + tx];
  __syncthreads();
  int t = t0 + tx;
  int c = t & 63;
  int kp = ((c >> 5) << 5) | (((c >> 2) & 3) << 3) | (((c >> 4) & 1) << 2) | (c & 3);
  size_t col = (size_t)(t & ~63) + kp;
#pragma unroll
  for (int i = 0; i < 32; i += 8)
    vT[(size_t)(c0 + ty + i) * M + col] = tile[tx][ty + i];
}

// ---------------- layernorm -> bf16 ----------------
__global__ void ln_bf16(const float* __restrict__ x, const float* __restrict__ g,
                        const float* __restrict__ be, unsigned short* __restrict__ out) {
  int row = blockIdx.x;
  const float* xr = x + (size_t)row * D_MODEL;
  int t = threadIdx.x;
  float v0 = xr[t], v1 = xr[t + 256], v2 = xr[t + 512];
  float s = v0 + v1 + v2;
  float s2 = v0 * v0 + v1 * v1 + v2 * v2;
#pragma unroll
  for (int off = 32; off > 0; off >>= 1) {
    s += __shfl_down(s, off, 64);
    s2 += __shfl_down(s2, off, 64);
  }
  __shared__ float red[8];
  int w = t >> 6, lane = t & 63;
  if (lane == 0) { red[w] = s; red[w + 4] = s2; }
  __syncthreads();
  if (t == 0) {
    float a = red[0] + red[1] + red[2] + red[3];
    float b = red[4] + red[5] + red[6] + red[7];
    red[0] = a * (1.0f / 768.0f);
    red[4] = b * (1.0f / 768.0f);
  }
  __syncthreads();
  float mu = red[0];
  float var = red[4] - mu * mu;
  float rs = rsqrtf(var + 1e-6f);
  unsigned short* orow = out + (size_t)row * D_MODEL;
  orow[t]       = f2bfbits((v0 - mu) * rs * g[t]       + be[t]);
  orow[t + 256] = f2bfbits((v1 - mu) * rs * g[t + 256] + be[t + 256]);
  orow[t + 512] = f2bfbits((v2 - mu) * rs * g[t + 512] + be[t + 512]);
}

// ---------------- bf16 MFMA GEMM 128x128, DMA-staged body (QKV, FC1) --------
// R7-proven: global_load_lds w=16 staging (pre-swizzled global source,
// linear LDS dest), asm ds_read frags, vmcnt(4)/barrier/lgkm(0)/barrier.
template <int EPI>
__device__ __forceinline__ void gemm128_body(
    const unsigned short* __restrict__ A, const unsigned short* __restrict__ Bt,
    const float* __restrict__ bias, const float* __restrict__ res,
    void* __restrict__ outv, int M, int N, int K) {
  __shared__ unsigned short lA[2][128 * 32];
  __shared__ unsigned short lB[2][128 * 32];
  int tid = threadIdx.x;
  int w = tid >> 6, lane = tid & 63;
  int id = blockIdx.x;
  int nn = N >> 7, bandM = (M >> 7) >> 3;
  int xcd = id & 7, s = id >> 3;
  int mt = xcd * bandM + s / nn;
  int nt = s - (s / nn) * nn;
  int m0 = mt * 128, n0 = nt * 128;
  int wm = (w >> 1) * 64, wn = (w & 1) * 64;
  f32x4 acc[4][4];
#pragma unroll
  for (int i = 0; i < 4; i++)
#pragma unroll
    for (int j = 0; j < 4; j++) acc[i][j] = (f32x4){0.f, 0.f, 0.f, 0.f};

  int fm = lane & 15, fg = lane >> 4;

  int r0s = w * 16 + (lane >> 2);
  int sc0 = (lane & 3) ^ ((r0s >> 1) & 3);
  const unsigned short* gAs = A + (size_t)(m0 + r0s) * K + sc0 * 8;
  const unsigned short* gBs = Bt + (size_t)(n0 + r0s) * K + sc0 * 8;
  char* lA0 = (char*)&lA[0][0];
  char* lB0 = (char*)&lB[0][0];
  int wo = w * 1024;
  int nk = K >> 5;

  auto stage = [&](int kt, int buf) {
    int kk = kt < nk ? kt : nk - 1;      // clamp: uniform vmcnt accounting
    int off = kk * 32;
    gload_lds16(gAs + off,                  lA0 + buf * 8192 + wo);
    gload_lds16(gAs + off + (size_t)64 * K, lA0 + buf * 8192 + 4096 + wo);
    gload_lds16(gBs + off,                  lB0 + buf * 8192 + wo);
    gload_lds16(gBs + off + (size_t)64 * K, lB0 + buf * 8192 + 4096 + wo);
  };

  const unsigned aoff0 = (unsigned)((wm + fm) * 64 + ((((wm + fm) >> 1) & 3) ^ fg) * 16);
  const unsigned boff0 = (unsigned)((wn + fm) * 64 + ((((wn + fm) >> 1) & 3) ^ fg) * 16);

  stage(0, 0);
  stage(1, 1);   // 8 outstanding

  for (int k = 0; k < nk; ++k) {
    int cur = k & 1;
    asm volatile("s_waitcnt vmcnt(4)");   // stage(k) landed; stage(k+1) in flight
    FENCE_();
    __builtin_amdgcn_s_barrier();         // every wave's DMA for buf[cur] done
    FENCE_();
    bf16x8 af[4], bfr[4];
    const lds_char* pa = (const lds_char*)(lA0 + cur * 8192 + aoff0);
    const lds_char* pb = (const lds_char*)(lB0 + cur * 8192 + boff0);
    DSR(af[0], pa, 0); DSR(af[1], pa, 1024); DSR(af[2], pa, 2048); DSR(af[3], pa, 3072);
    DSR(bfr[0], pb, 0); DSR(bfr[1], pb, 1024); DSR(bfr[2], pb, 2048); DSR(bfr[3], pb, 3072);
    asm volatile("s_waitcnt lgkmcnt(0)");
    FENCE_();
    __builtin_amdgcn_s_barrier();         // all reads done -> buf[cur] reusable
    FENCE_();
    stage(k + 2, cur);
    FENCE_();
#pragma unroll
    for (int i = 0; i < 4; ++i)
#pragma unroll
      for (int j = 0; j < 4; ++j)
        acc[i][j] = __builtin_amdgcn_mfma_f32_16x16x32_bf16(af[i], bfr[j], acc[i][j], 0, 0, 0);
  }
  asm volatile("s_waitcnt vmcnt(0)");     // drain DMA before exit
  FENCE_();

  int er = (lane >> 4) * 4, ec = lane & 15;
#pragma unroll
  for (int i = 0; i < 4; i++) {
#pragma unroll
    for (int j = 0; j < 4; j++) {
      int n = n0 + wn + j * 16 + ec;
      float bv = bias[n];
#pragma unroll
      for (int r = 0; r < 4; r++) {
        int m = m0 + wm + i * 16 + er + r;
        float v = acc[i][j][r] + bv;
        if (EPI == 1) {
          v += res[(size_t)m * N + n];
          ((float*)outv)[(size_t)m * N + n] = v;
        } else {
          if (EPI == 2) v = 0.5f * v * (1.0f + erff(v * 0.70710678118f));
          ((unsigned short*)outv)[(size_t)m * N + n] = f2bfbits(v);
        }
      }
    }
  }
}

__global__ void __launch_bounds__(256, 3)
gemm_qkv(const unsigned short* __restrict__ A, const unsigned short* __restrict__ Bt,
         const float* __restrict__ bias, void* __restrict__ outv, int M, int N, int K) {
  gemm128_body<0>(A, Bt, bias, nullptr, outv, M, N, K);
}
__global__ void __launch_bounds__(256, 3)
gemm_fc1(const unsigned short* __restrict__ A, const unsigned short* __restrict__ Bt,
         const float* __restrict__ bias, void* __restrict__ outv, int M, int N, int K) {
  gemm128_body<2>(A, Bt, bias, nullptr, outv, M, N, K);
}

// ---------------- bf16 MFMA GEMM 128x64, register-staged body (Wo, FC2) -----
// R8-proven best for the N=768 GEMMs (65us vs DMA's 71 at 2- and 3-deep).
__device__ __forceinline__ void gemm64_body(
    const unsigned short* __restrict__ A, const unsigned short* __restrict__ Bt,
    const float* __restrict__ bias, const float* __restrict__ res,
    float* __restrict__ outv, int M, int N, int K) {
  __shared__ unsigned short lA[2][128 * 32];
  __shared__ unsigned short lB[2][64 * 32];
  int tid = threadIdx.x;
  int w = tid >> 6, lane = tid & 63;
  int id = blockIdx.x;
  int nn = N >> 6, bandM = (M >> 7) >> 3;
  int xcd = id & 7, s = id >> 3;
  int mt = xcd * bandM + s / nn;
  int nt = s - (s / nn) * nn;
  int m0 = mt * 128, n0 = nt * 64;
  int wm = w * 32;
  f32x4 acc[2][4];
#pragma unroll
  for (int i = 0; i < 2; i++)
#pragma unroll
    for (int j = 0; j < 4; j++) acc[i][j] = (f32x4){0.f, 0.f, 0.f, 0.f};

  int sr = tid >> 2, sc = tid & 3;
  const unsigned short* gA = A + (size_t)(m0 + sr) * K + sc * 8;
  const unsigned short* gB = Bt + (size_t)(n0 + sr) * K + sc * 8;  // sr<64: whole B tile
  int wOff = sr * 64 + ((((sr >> 1) & 3) ^ sc) * 16);
  int fm = lane & 15, fg = lane >> 4;

  uint4 pA0, pA1, pB0;
  uint4 qA0, qA1, qB0;

  int nk = K >> 5;
  pA0 = *(const uint4*)(gA);
  pA1 = *(const uint4*)(gA + (size_t)64 * K);
  pB0 = *(const uint4*)(gB);
  qA0 = *(const uint4*)(gA + 32);
  qA1 = *(const uint4*)(gA + (size_t)64 * K + 32);
  qB0 = *(const uint4*)(gB + 32);

  for (int k = 0; k < nk; k += 2) {
    {
      char* la = (char*)&lA[0][0];
      char* lb = (char*)&lB[0][0];
      *(uint4*)(la + wOff) = pA0;
      *(uint4*)(la + wOff + 4096) = pA1;
      *(uint4*)(lb + wOff) = pB0;
      if (k + 2 < nk) {
        int k0 = (k + 2) * 32;
        pA0 = *(const uint4*)(gA + k0);
        pA1 = *(const uint4*)(gA + (size_t)64 * K + k0);
        pB0 = *(const uint4*)(gB + k0);
      }
      store_sync();
      bf16x8 af[2], bfr[4];
#pragma unroll
      for (int i = 0; i < 2; i++) {
        int rr = wm + i * 16 + fm;
        af[i] = *(const bf16x8*)(la + rr * 64 + ((((rr >> 1) & 3) ^ fg) * 16));
      }
#pragma unroll
      for (int j = 0; j < 4; j++) {
        int rr = j * 16 + fm;
        bfr[j] = *(const bf16x8*)(lb + rr * 64 + ((((rr >> 1) & 3) ^ fg) * 16));
      }
#pragma unroll
      for (int i = 0; i < 2; i++)
#pragma unroll
        for (int j = 0; j < 4; j++)
          acc[i][j] = __builtin_amdgcn_mfma_f32_16x16x32_bf16(af[i], bfr[j], acc[i][j], 0, 0, 0);
      store_sync();
    }
    {
      char* la = (char*)&lA[1][0];
      char* lb = (char*)&lB[1][0];
      *(uint4*)(la + wOff) = qA0;
      *(uint4*)(la + wOff + 4096) = qA1;
      *(uint4*)(lb + wOff) = qB0;
      if (k + 3 < nk) {
        int k0 = (k + 3) * 32;
        qA0 = *(const uint4*)(gA + k0);
        qA1 = *(const uint4*)(gA + (size_t)64 * K + k0);
        qB0 = *(const uint4*)(gB + k0);
      }
      store_sync();
      bf16x8 af[2], bfr[4];
#pragma unroll
      for (int i = 0; i < 2; i++) {
        int rr = wm + i * 16 + fm;
        af[i] = *(const bf16x8*)(la + rr * 64 + ((((rr >> 1) & 3) ^ fg) * 16));
      }
#pragma unroll
      for (int j = 0; j < 4; j++) {
        int rr = j * 16 + fm;
        bfr[j] = *(const bf16x8*)(lb + rr * 64 + ((((rr >> 1) & 3) ^ fg) * 16));
      }
#pragma unroll
      for (int i = 0; i < 2; i++)
#pragma unroll
        for (int j = 0; j < 4; j++)
          acc[i][j] = __builtin_amdgcn_mfma_f32_16x16x32_bf16(af[i], bfr[j], acc[i][j], 0, 0, 0);
      store_sync();
    }
  }

  int er = (lane >> 4) * 4, ec = lane & 15;
#pragma unroll
  for (int i = 0; i < 2; i++) {
#pragma unroll
    for (int j = 0; j < 4; j++) {
      int n = n0 + j * 16 + ec;
      float bv = bias[n];
#pragma unroll
      for (int r = 0; r < 4; r++) {
        int m = m0 + wm + i * 16 + er + r;
        float v = acc[i][j][r] + bv + res[(size_t)m * N + n];
        outv[(size_t)m * N + n] = v;
      }
    }
  }
}

__global__ void __launch_bounds__(256, 4)
gemm_wo(const unsigned short* __restrict__ A, const unsigned short* __restrict__ Bt,
        const float* __restrict__ bias, const float* __restrict__ res,
        float* __restrict__ outv, int M, int N, int K) {
  gemm64_body(A, Bt, bias, res, outv, M, N, K);
}
__global__ void __launch_bounds__(256, 4)
gemm_fc2(const unsigned short* __restrict__ A, const unsigned short* __restrict__ Bt,
         const float* __restrict__ bias, const float* __restrict__ res,
         float* __restrict__ outv, int M, int N, int K) {
  gemm64_body(A, Bt, bias, res, outv, M, N, K);
}

// ---------------- ragged flash attention v4 (unchanged) ---------------------
__global__ void attn_flash4(const unsigned short* __restrict__ qkv,
                            const unsigned short* __restrict__ vT,
                            const int* __restrict__ cu,
                            unsigned short* __restrict__ out, int M) {
  int id = blockIdx.x;
  int qc = id / 96;
  int bh = id - qc * 96;
  int b = bh / 12, h = bh - b * 12;
  int tok0 = cu[b];
  int len = cu[b + 1] - tok0;
  if (qc * 128 >= len) return;

  __shared__ unsigned short lK[2][64 * 64];
  __shared__ unsigned short lVT[2][64 * 64];

  int tid = threadIdx.x, w = tid >> 6, lane = tid & 63;
  int fm = lane & 15, fg = lane >> 4;
  int xm = fm & 7;
  int qbase = qc * 128 + w * 32;

  bf16x8 qf[2][2];
#pragma unroll
  for (int qs = 0; qs < 2; qs++)
#pragma unroll
    for (int kh = 0; kh < 2; kh++)
      qf[qs][kh] = *(const bf16x8*)(qkv + (size_t)(tok0 + qbase + qs * 16 + fm) * N_QKV +
                                    h * 64 + kh * 32 + fg * 8);

  f32x4 Oacc[2][4];
#pragma unroll
  for (int qs = 0; qs < 2; qs++)
#pragma unroll
    for (int dt = 0; dt < 4; dt++) Oacc[qs][dt] = (f32x4){0.f, 0.f, 0.f, 0.f};
  float lrow[2] = {0.f, 0.f};
  const float C2 = 0.18033688011112042f;  // log2(e)/sqrt(64)

  int sr = tid >> 3, sp = tid & 7, sl = sp ^ (sr & 7);
  const unsigned short* kg0 = qkv + D_MODEL + h * 64 + sl * 8;
  const unsigned short* vg0 = vT + (size_t)(h * 64 + sr) * M + tok0 + sl * 8;

  uint4 rk0, rk1, rv0, rv1;
  auto gload = [&](int kt) {
    rk0 = *(const uint4*)(kg0 + (size_t)(tok0 + kt + sr) * N_QKV);
    rk1 = *(const uint4*)(kg0 + (size_t)(tok0 + kt + sr + 32) * N_QKV);
    rv0 = *(const uint4*)(vg0 + kt);
    rv1 = *(const uint4*)(vg0 + (size_t)32 * M + kt);
  };

  int nkt = len >> 6;
  gload(0);
  for (int kt = 0; kt < nkt; kt++) {
    int cur = kt & 1;
    *(uint4*)((char*)&lK[cur][0] + tid * 16) = rk0;
    *(uint4*)((char*)&lK[cur][0] + tid * 16 + 4096) = rk1;
    *(uint4*)((char*)&lVT[cur][0] + tid * 16) = rv0;
    *(uint4*)((char*)&lVT[cur][0] + tid * 16 + 4096) = rv1;
    if (kt + 1 < nkt) gload((kt + 1) * 64);
    store_sync();

    f32x4 s[2][4];
#pragma unroll
    for (int qs = 0; qs < 2; qs++)
#pragma unroll
      for (int t = 0; t < 4; t++) s[qs][t] = (f32x4){0.f, 0.f, 0.f, 0.f};
#pragma unroll
    for (int t = 0; t < 4; t++) {
      bf16x8 kf0 = *(const bf16x8*)&lK[cur][(t * 16 + fm) * 64 + ((fg ^ xm) * 8)];
      bf16x8 kf1 = *(const bf16x8*)&lK[cur][(t * 16 + fm) * 64 + (((4 + fg) ^ xm) * 8)];
#pragma unroll
      for (int qs = 0; qs < 2; qs++) {
        s[qs][t] = __builtin_amdgcn_mfma_f32_16x16x32_bf16(kf0, qf[qs][0], s[qs][t], 0, 0, 0);
        s[qs][t] = __builtin_amdgcn_mfma_f32_16x16x32_bf16(kf1, qf[qs][1], s[qs][t], 0, 0, 0);
      }
    }

    union { bf16x8 v; unsigned u[4]; } af[2][2];
#pragma unroll
    for (int qs = 0; qs < 2; qs++) {
      float ssum = 0.f;
#pragma unroll
      for (int t = 0; t < 4; t++) {
#pragma unroll
        for (int r = 0; r < 4; r++) {
          float p = exp2f(s[qs][t][r] * C2);
          s[qs][t][r] = p;
          ssum += p;
        }
      }
      lrow[qs] += ssum;
      af[qs][0].u[0] = pk2(s[qs][0][0], s[qs][0][1]);
      af[qs][0].u[1] = pk2(s[qs][0][2], s[qs][0][3]);
      af[qs][0].u[2] = pk2(s[qs][1][0], s[qs][1][1]);
      af[qs][0].u[3] = pk2(s[qs][1][2], s[qs][1][3]);
      af[qs][1].u[0] = pk2(s[qs][2][0], s[qs][2][1]);
      af[qs][1].u[1] = pk2(s[qs][2][2], s[qs][2][3]);
      af[qs][1].u[2] = pk2(s[qs][3][0], s[qs][3][1]);
      af[qs][1].u[3] = pk2(s[qs][3][2], s[qs][3][3]);
    }

#pragma unroll
    for (int dt = 0; dt < 4; dt++) {
      bf16x8 vf0 = *(const bf16x8*)&lVT[cur][(dt * 16 + fm) * 64 + ((fg ^ xm) * 8)];
      bf16x8 vf1 = *(const bf16x8*)&lVT[cur][(dt * 16 + fm) * 64 + (((4 + fg) ^ xm) * 8)];
#pragma unroll
      for (int qs = 0; qs < 2; qs++) {
        Oacc[qs][dt] = __builtin_amdgcn_mfma_f32_16x16x32_bf16(af[qs][0].v, vf0, Oacc[qs][dt], 0, 0, 0);
        Oacc[qs][dt] = __builtin_amdgcn_mfma_f32_16x16x32_bf16(af[qs][1].v, vf1, Oacc[qs][dt], 0, 0, 0);
      }
    }
  }

#pragma unroll
  for (int qs = 0; qs < 2; qs++) {
    lrow[qs] += __shfl_xor(lrow[qs], 16, 64);
    lrow[qs] += __shfl_xor(lrow[qs], 32, 64);
    float inv = 1.0f / lrow[qs];
    float ir[4];
#pragma unroll
    for (int r = 0; r < 4; r++) ir[r] = __shfl(inv, fg * 4 + r, 64);
#pragma unroll
    for (int dt = 0; dt < 4; dt++)
#pragma unroll
      for (int r = 0; r < 4; r++)
        out[(size_t)(tok0 + qbase + qs * 16 + fg * 4 + r) * D_MODEL + h * 64 + dt * 16 + fm] =
            f2bfbits(Oacc[qs][dt][r] * ir[r]);
  }
}

extern "C" void kernel_launch(void* const* d_in, const int* in_sizes, int n_in,
                              void* d_out, int out_size, void* d_ws, size_t ws_size,
                              hipStream_t stream) {
  const float* x    = (const float*)d_in[0];
  const int* cu     = (const int*)d_in[1];
  const float* g1   = (const float*)d_in[2];
  const float* be1  = (const float*)d_in[3];
  const float* Wqkv = (const float*)d_in[4];
  const float* bqkv = (const float*)d_in[5];
  const float* Wo   = (const float*)d_in[6];
  const float* bo   = (const float*)d_in[7];
  const float* g2   = (const float*)d_in[8];
  const float* be2  = (const float*)d_in[9];
  const float* W1   = (const float*)d_in[10];
  const float* bfc1 = (const float*)d_in[11];
  const float* W2   = (const float*)d_in[12];
  const float* bfc2 = (const float*)d_in[13];
  float* out = (float*)d_out;
  int M = in_sizes[0] / D_MODEL;  // 6144

  unsigned short* WqkvT = (unsigned short*)d_ws;                       // 2304x768
  unsigned short* WoT   = WqkvT + 2304 * 768;                          // 768x768
  unsigned short* W1T   = WoT + 768 * 768;                             // 3072x768
  unsigned short* W2T   = W1T + 3072 * 768;                            // 768x3072
  unsigned short* bufA  = W2T + 768 * 3072;                            // M x 768 bf16
  float* x1             = (float*)(bufA + (size_t)M * D_MODEL);        // M x 768 f32
  unsigned short* qkvb  = (unsigned short*)(x1 + (size_t)M * D_MODEL); // M x 2304/3072 bf16
  unsigned short* vT = (unsigned short*)x1;  // overlaps x1 (dead before Wo-gemm)

  transpose_w4<<<6912, dim3(32, 8), 0, stream>>>(Wqkv, Wo, W1, W2, WqkvT, WoT, W1T, W2T);

  ln_bf16<<<M, 256, 0, stream>>>(x, g1, be1, bufA);
  gemm_qkv<<<(2304 / 128) * (M / 128), 256, 0, stream>>>(bufA, WqkvT, bqkv, qkvb, M, 2304, 768);
  transpose_v<<<dim3(M / 32, 768 / 32), dim3(32, 8), 0, stream>>>(qkvb, vT, M);
  attn_flash4<<<8 * 96, 256, 0, stream>>>(qkvb, vT, cu, bufA, M);
  gemm_wo<<<(768 / 64) * (M / 128), 256, 0, stream>>>(bufA, WoT, bo, x, x1, M, 768, 768);
  ln_bf16<<<M, 256, 0, stream>>>(x1, g2, be2, bufA);
  gemm_fc1<<<(3072 / 128) * (M / 128), 256, 0, stream>>>(bufA, W1T, bfc1, qkvb, M, 3072, 768);
  gemm_fc2<<<(768 / 64) * (M / 128), 256, 0, stream>>>(qkvb, W2T, bfc2, x1, out, M, 768, 3072);
}